// Round 1
// baseline (596.729 us; speedup 1.0000x reference)
//
#include <hip/hip_runtime.h>

// Problem constants
#define NUMK 8
#define IDXREF 4
constexpr int Bn = 4, CG = 16, HH = 384, WW = 384;
constexpr int HWSZ = HH * WW;          // 147456
constexpr int COUT = 24;               // 3*num conv output channels

// ---------------------------------------------------------------------------
// Kernel A: 3x3 SAME conv (16 -> 24) + bias.
// Writes conv channels 0..15 (the offsets) into d_out's offset_out layout
// (B,18,H,W): conv ch c -> out ch c for c<8, out ch c+2 for c>=8; out ch 8,9 = 0.
// Writes conv channels 16..23 (aff) into ws as (B,8,HW) planes.
// Weights are read with wave-uniform indices -> scalar loads + SGPR fma operand.
// ---------------------------------------------------------------------------
__global__ __launch_bounds__(256) void conv_kernel(
    const float* __restrict__ g, const float* __restrict__ Wc,
    const float* __restrict__ bc, float* __restrict__ out_off,
    float* __restrict__ affc) {
  int idx = blockIdx.x * blockDim.x + threadIdx.x;
  if (idx >= Bn * HWSZ) return;
  int b = idx / HWSZ, p = idx % HWSZ;
  int h = p / WW, w = p % WW;

  float acc[COUT];
#pragma unroll
  for (int oc = 0; oc < COUT; ++oc) acc[oc] = bc[oc];

  const float* gb = g + (size_t)b * CG * HWSZ;
  for (int ic = 0; ic < CG; ++ic) {
    const float* gc = gb + (size_t)ic * HWSZ;
#pragma unroll
    for (int t = 0; t < 9; ++t) {
      int dy = t / 3 - 1, dx = t % 3 - 1;
      int y = h + dy, x = w + dx;
      float v = (y >= 0 && y < HH && x >= 0 && x < WW) ? gc[y * WW + x] : 0.f;
#pragma unroll
      for (int oc = 0; oc < COUT; ++oc)
        acc[oc] += v * Wc[(oc * CG + ic) * 9 + t];
    }
  }

  float* ob = out_off + (size_t)b * 18 * HWSZ;
#pragma unroll
  for (int c = 0; c < 16; ++c) {
    int c18 = (c < 8) ? c : c + 2;
    ob[(size_t)c18 * HWSZ + p] = acc[c];
  }
  ob[(size_t)8 * HWSZ + p] = 0.f;
  ob[(size_t)9 * HWSZ + p] = 0.f;
  float* ab = affc + (size_t)b * 8 * HWSZ;
#pragma unroll
  for (int c = 0; c < 8; ++c) ab[(size_t)c * HWSZ + p] = acc[16 + c];
}

// Bilinear sample with zero padding, exactly matching the reference:
// valid per-corner if coord in [0, H-1]; clip index; weight *= valid.
__device__ __forceinline__ float bilin_zero(const float* __restrict__ img,
                                            float iy, float ix) {
  float y0f = floorf(iy), x0f = floorf(ix);
  float wy1 = iy - y0f, wx1 = ix - x0f;
  int y0 = (int)y0f, x0 = (int)x0f;
  float acc = 0.f;
#pragma unroll
  for (int dy = 0; dy < 2; ++dy) {
    int yc = y0 + dy;
    bool vy = (yc >= 0) && (yc <= HH - 1);
    int yi = min(max(yc, 0), HH - 1);
    float wy = dy ? wy1 : 1.f - wy1;
#pragma unroll
    for (int dx = 0; dx < 2; ++dx) {
      int xc = x0 + dx;
      bool vx = (xc >= 0) && (xc <= WW - 1);
      int xi = min(max(xc, 0), WW - 1);
      float wx = dx ? wx1 : 1.f - wx1;
      float v = img[yi * WW + xi];
      acc += v * (wy * wx) * ((vy && vx) ? 1.f : 0.f);
    }
  }
  return acc;
}

// ---------------------------------------------------------------------------
// Kernel B: everything else, one thread per (b, p).
// cos_w[c] = sum_j fea[b,j,p] * Bilin(fea[b,a], y=dx_c(r)+cb, x=dy_c(r)+cb)
//   with m=8p: a = m/HW (const over j), r = m%HW + j, cb = (c<4? row(r):col(r)).
// Then conf gather at pixel p, tanh/4, abs-sum normalize, ref channel, softmax.
// ---------------------------------------------------------------------------
__global__ __launch_bounds__(256) void main_kernel(
    const float* __restrict__ fea, const float* __restrict__ conf_img,
    const float* __restrict__ out_off, const float* __restrict__ affc,
    const float* __restrict__ aff_scale, float* __restrict__ out_aff) {
  int idx = blockIdx.x * blockDim.x + threadIdx.x;
  if (idx >= Bn * HWSZ) return;
  int b = idx / HWSZ, p = idx % HWSZ;
  int h = p / WW, w = p % WW;

  const float* feab = fea + (size_t)b * 8 * HWSZ;
  float feaj[8];
#pragma unroll
  for (int j = 0; j < 8; ++j) feaj[j] = feab[(size_t)j * HWSZ + p];

  int m0 = 8 * p;
  int a = m0 / HWSZ;
  int r0 = m0 - a * HWSZ;
  const float* imgA = feab + (size_t)a * HWSZ;
  const float* offb = out_off + (size_t)b * 18 * HWSZ;

  float cw[8];
#pragma unroll
  for (int c = 0; c < 8; ++c) cw[c] = 0.f;

  for (int j = 0; j < 8; ++j) {
    int r = r0 + j;
    int hr = r / WW, wr = r - hr * WW;
    float fj = feaj[j];
    float cbr = (float)hr, cbc = (float)wr;
#pragma unroll
    for (int c = 0; c < 8; ++c) {
      float cb = (c < 4) ? cbr : cbc;
      int chy = (c < 4) ? 2 * c : 2 * c + 2;  // d_out channel of dy_c
      float dy = offb[(size_t)chy * HWSZ + r];
      float dx = offb[(size_t)(chy + 1) * HWSZ + r];
      float ix = dy + cb;  // x coordinate (reference xy_off[...,0])
      float iy = dx + cb;  // y coordinate (reference xy_off[...,1])
      cw[c] += fj * bilin_zero(imgA, iy, ix);
    }
  }

  const float* cimg = conf_img + (size_t)b * HWSZ;
  const float* acb = affc + (size_t)b * 8 * HWSZ;
  float denom = aff_scale[0] + 1e-8f;

  float t[8];
  float asum = 0.f;
#pragma unroll
  for (int c = 0; c < 8; ++c) {
    int chy = (c < 4) ? 2 * c : 2 * c + 2;
    float dy = offb[(size_t)chy * HWSZ + p];
    float dx = offb[(size_t)(chy + 1) * HWSZ + p];
    float cf = bilin_zero(cimg, dy + (float)h, dx + (float)w);
    float av = acb[(size_t)c * HWSZ + p] * cw[c];
    float tv = tanhf(av) / denom * cf;
    t[c] = tv;
    asum += fabsf(tv);
  }
  asum += 1e-4f;
  asum = fmaxf(asum, 1.f);
  float ssum = 0.f;
#pragma unroll
  for (int c = 0; c < 8; ++c) {
    t[c] /= asum;
    ssum += t[c];
  }

  float v9[9];
#pragma unroll
  for (int c = 0; c < 4; ++c) v9[c] = t[c];
  v9[4] = 1.f - ssum;
#pragma unroll
  for (int c = 4; c < 8; ++c) v9[c + 1] = t[c];

  float mx = v9[0];
#pragma unroll
  for (int i = 1; i < 9; ++i) mx = fmaxf(mx, v9[i]);
  float es = 0.f;
#pragma unroll
  for (int i = 0; i < 9; ++i) {
    v9[i] = expf(v9[i] - mx);
    es += v9[i];
  }
  float inv = 1.f / es;
  float* ob = out_aff + (size_t)b * 9 * HWSZ;
#pragma unroll
  for (int i = 0; i < 9; ++i) ob[(size_t)i * HWSZ + p] = v9[i] * inv;
}

extern "C" void kernel_launch(void* const* d_in, const int* in_sizes, int n_in,
                              void* d_out, int out_size, void* d_ws,
                              size_t ws_size, hipStream_t stream) {
  const float* guidance = (const float*)d_in[0];  // (4,16,384,384)
  const float* conf_img = (const float*)d_in[1];  // (4,1,384,384)
  const float* fea = (const float*)d_in[2];       // (4,8,384,384)
  const float* Wc = (const float*)d_in[3];        // (24,16,3,3)
  const float* bc = (const float*)d_in[4];        // (24,)
  const float* ascale = (const float*)d_in[5];    // (1,)

  float* out = (float*)d_out;
  float* out_off = out;                             // (4,18,384,384)
  float* out_aff = out + (size_t)Bn * 18 * HWSZ;    // (4,9,384,384)
  float* affc = (float*)d_ws;                       // (4,8,HW) = 18.9 MB

  int total = Bn * HWSZ;
  int blk = 256;
  int grd = (total + blk - 1) / blk;
  conv_kernel<<<grd, blk, 0, stream>>>(guidance, Wc, bc, out_off, affc);
  main_kernel<<<grd, blk, 0, stream>>>(fea, conf_img, out_off, affc, ascale,
                                       out_aff);
}

// Round 2
// 326.656 us; speedup vs baseline: 1.8268x; 1.8268x over previous
//
#include <hip/hip_runtime.h>

#define NUMK 8
#define IDXREF 4
constexpr int Bn = 4, CG = 16, HH = 384, WW = 384;
constexpr int HWSZ = HH * WW;  // 147456
constexpr int COUT = 24;
constexpr int TS = 16;  // conv output tile

// ---------------------------------------------------------------------------
// Weight transpose: Wt[(ic*9+t)*24 + oc] = Wc[(oc*16+ic)*9 + t]
// ---------------------------------------------------------------------------
__global__ void wtrans_kernel(const float* __restrict__ Wc,
                              float* __restrict__ Wt) {
  int i = blockIdx.x * 256 + threadIdx.x;
  if (i < COUT * CG * 9) {
    int oc = i / (CG * 9), rem = i % (CG * 9);
    Wt[rem * COUT + oc] = Wc[i];
  }
}

// ---------------------------------------------------------------------------
// Conv 3x3 SAME, 16->24, LDS-tiled. Writes offsets into d_out layout
// (ch c -> c for c<8, c+2 for c>=8; ch 8,9 zero), aff channels into ws.
// ---------------------------------------------------------------------------
__global__ __launch_bounds__(256) void conv_kernel(
    const float* __restrict__ g, const float* __restrict__ Wt,
    const float* __restrict__ bc, float* __restrict__ out_off,
    float* __restrict__ affc) {
  __shared__ float lds[CG][18][18];
  int bi = blockIdx.x;
  int bx = (bi % (WW / TS)) * TS;
  int by = ((bi / (WW / TS)) % (HH / TS)) * TS;
  int b = bi / ((WW / TS) * (HH / TS));
  const float* gb = g + (size_t)b * CG * HWSZ;

  for (int idx = threadIdx.x; idx < CG * 18 * 18; idx += 256) {
    int ic = idx / 324, rem = idx % 324, y = rem / 18, x = rem % 18;
    int gy = by + y - 1, gx = bx + x - 1;
    float v = (gy >= 0 && gy < HH && gx >= 0 && gx < WW)
                  ? gb[(size_t)ic * HWSZ + gy * WW + gx]
                  : 0.f;
    lds[ic][y][x] = v;
  }
  __syncthreads();

  int w = threadIdx.x % TS, h = threadIdx.x / TS;
  float acc[COUT];
#pragma unroll
  for (int oc = 0; oc < COUT; ++oc) acc[oc] = bc[oc];

  for (int ic = 0; ic < CG; ++ic) {
#pragma unroll
    for (int t = 0; t < 9; ++t) {
      float v = lds[ic][h + t / 3][w + t % 3];
      const float* wp = Wt + (ic * 9 + t) * COUT;
#pragma unroll
      for (int oc = 0; oc < COUT; ++oc) acc[oc] += v * wp[oc];
    }
  }

  int p = (by + h) * WW + (bx + w);
  float* ob = out_off + (size_t)b * 18 * HWSZ;
#pragma unroll
  for (int c = 0; c < 16; ++c) {
    int c18 = (c < 8) ? c : c + 2;
    ob[(size_t)c18 * HWSZ + p] = acc[c];
  }
  ob[(size_t)8 * HWSZ + p] = 0.f;
  ob[(size_t)9 * HWSZ + p] = 0.f;
  float* ab = affc + (size_t)b * 8 * HWSZ;
#pragma unroll
  for (int c = 0; c < 8; ++c) ab[(size_t)c * HWSZ + p] = acc[16 + c];
}

// Bilinear sample, zero padding — identical math to the reference.
__device__ __forceinline__ float bilin_zero(const float* __restrict__ img,
                                            float iy, float ix) {
  float y0f = floorf(iy), x0f = floorf(ix);
  float wy1 = iy - y0f, wx1 = ix - x0f;
  int y0 = (int)y0f, x0 = (int)x0f;
  float acc = 0.f;
#pragma unroll
  for (int dy = 0; dy < 2; ++dy) {
    int yc = y0 + dy;
    bool vy = (yc >= 0) && (yc <= HH - 1);
    int yi = min(max(yc, 0), HH - 1);
    float wy = dy ? wy1 : 1.f - wy1;
#pragma unroll
    for (int dx = 0; dx < 2; ++dx) {
      int xc = x0 + dx;
      bool vx = (xc >= 0) && (xc <= WW - 1);
      int xi = min(max(xc, 0), WW - 1);
      float wx = dx ? wx1 : 1.f - wx1;
      float v = img[yi * WW + xi];
      acc += v * (wy * wx) * ((vy && vx) ? 1.f : 0.f);
    }
  }
  return acc;
}

// ---------------------------------------------------------------------------
// cw for c=4..7, lane-remapped so all lanes share wr (gathers cluster).
// lane L -> Lp = Lblk*64+L (the row hr), wave w -> m = mblk*4+w.
// p = a*18432 + 48*Lp + m ; r0 = 384*Lp + 8*m ; wr = 8*m + j (lane-uniform).
// ---------------------------------------------------------------------------
__global__ __launch_bounds__(256) void cw47_kernel(
    const float* __restrict__ fea, const float* __restrict__ out_off,
    float* __restrict__ cw4) {
  int lane = threadIdx.x & 63, wv = threadIdx.x >> 6;
  int bi = blockIdx.x;
  int Lblk = bi % 6;
  bi /= 6;
  int mblk = bi % 12;
  bi /= 12;
  int a = bi % 8, b = bi / 8;
  int m = mblk * 4 + wv;
  int Lp = Lblk * 64 + lane;
  int p = a * 18432 + 48 * Lp + m;
  int r0 = 384 * Lp + 8 * m;

  const float* feab = fea + (size_t)b * 8 * HWSZ;
  const float* imgA = feab + (size_t)a * HWSZ;
  const float* offb = out_off + (size_t)b * 18 * HWSZ;

  float feaj[8];
#pragma unroll
  for (int j = 0; j < 8; ++j) feaj[j] = feab[(size_t)j * HWSZ + p];

  float cw[4];
#pragma unroll
  for (int c = 4; c < 8; ++c) {
    int chy = 2 * c + 2;
    const float* dyp = offb + (size_t)chy * HWSZ + r0;
    const float* dxp = offb + (size_t)(chy + 1) * HWSZ + r0;
    float4 dy0 = *(const float4*)dyp, dy1 = *(const float4*)(dyp + 4);
    float4 dx0 = *(const float4*)dxp, dx1 = *(const float4*)(dxp + 4);
    float dyv[8] = {dy0.x, dy0.y, dy0.z, dy0.w, dy1.x, dy1.y, dy1.z, dy1.w};
    float dxv[8] = {dx0.x, dx0.y, dx0.z, dx0.w, dx1.x, dx1.y, dx1.z, dx1.w};
    float s = 0.f;
#pragma unroll
    for (int j = 0; j < 8; ++j) {
      float cb = (float)(8 * m + j);
      s += feaj[j] * bilin_zero(imgA, dxv[j] + cb, dyv[j] + cb);
    }
    cw[c - 4] = s;
  }
#pragma unroll
  for (int c = 0; c < 4; ++c)
    cw4[(size_t)(b * 4 + c) * HWSZ + p] = cw[c];
}

// ---------------------------------------------------------------------------
// Main: cw for c=0..3 (p-contiguous mapping; samples cluster near (hr,hr)),
// conf gather, tanh / abs-norm / ref-channel / softmax epilogue.
// ---------------------------------------------------------------------------
__global__ __launch_bounds__(256) void main2_kernel(
    const float* __restrict__ fea, const float* __restrict__ conf_img,
    const float* __restrict__ out_off, const float* __restrict__ affc,
    const float* __restrict__ cw4, const float* __restrict__ aff_scale,
    float* __restrict__ out_aff) {
  int idx = blockIdx.x * blockDim.x + threadIdx.x;
  if (idx >= Bn * HWSZ) return;
  int b = idx / HWSZ, p = idx % HWSZ;
  int h = p / WW, w = p % WW;

  const float* feab = fea + (size_t)b * 8 * HWSZ;
  float feaj[8];
#pragma unroll
  for (int j = 0; j < 8; ++j) feaj[j] = feab[(size_t)j * HWSZ + p];

  int m0 = 8 * p;
  int a = m0 / HWSZ;
  int r0 = m0 - a * HWSZ;
  int hr = r0 / WW;  // constant over j (r0 is 8-aligned, row has 384 cols)
  const float* imgA = feab + (size_t)a * HWSZ;
  const float* offb = out_off + (size_t)b * 18 * HWSZ;

  float cw[8];
#pragma unroll
  for (int c = 0; c < 4; ++c) {
    int chy = 2 * c;
    const float* dyp = offb + (size_t)chy * HWSZ + r0;
    const float* dxp = offb + (size_t)(chy + 1) * HWSZ + r0;
    float4 dy0 = *(const float4*)dyp, dy1 = *(const float4*)(dyp + 4);
    float4 dx0 = *(const float4*)dxp, dx1 = *(const float4*)(dxp + 4);
    float dyv[8] = {dy0.x, dy0.y, dy0.z, dy0.w, dy1.x, dy1.y, dy1.z, dy1.w};
    float dxv[8] = {dx0.x, dx0.y, dx0.z, dx0.w, dx1.x, dx1.y, dx1.z, dx1.w};
    float cb = (float)hr;
    float s = 0.f;
#pragma unroll
    for (int j = 0; j < 8; ++j)
      s += feaj[j] * bilin_zero(imgA, dxv[j] + cb, dyv[j] + cb);
    cw[c] = s;
  }
#pragma unroll
  for (int c = 4; c < 8; ++c)
    cw[c] = cw4[(size_t)(b * 4 + (c - 4)) * HWSZ + p];

  const float* cimg = conf_img + (size_t)b * HWSZ;
  const float* acb = affc + (size_t)b * 8 * HWSZ;
  float denom = aff_scale[0] + 1e-8f;

  float t[8];
  float asum = 0.f;
#pragma unroll
  for (int c = 0; c < 8; ++c) {
    int chy = (c < 4) ? 2 * c : 2 * c + 2;
    float dy = offb[(size_t)chy * HWSZ + p];
    float dx = offb[(size_t)(chy + 1) * HWSZ + p];
    float cf = bilin_zero(cimg, dy + (float)h, dx + (float)w);
    float av = acb[(size_t)c * HWSZ + p] * cw[c];
    float tv = tanhf(av) / denom * cf;
    t[c] = tv;
    asum += fabsf(tv);
  }
  asum += 1e-4f;
  asum = fmaxf(asum, 1.f);
  float ssum = 0.f;
#pragma unroll
  for (int c = 0; c < 8; ++c) {
    t[c] /= asum;
    ssum += t[c];
  }

  float v9[9];
#pragma unroll
  for (int c = 0; c < 4; ++c) v9[c] = t[c];
  v9[4] = 1.f - ssum;
#pragma unroll
  for (int c = 4; c < 8; ++c) v9[c + 1] = t[c];

  float mx = v9[0];
#pragma unroll
  for (int i = 1; i < 9; ++i) mx = fmaxf(mx, v9[i]);
  float es = 0.f;
#pragma unroll
  for (int i = 0; i < 9; ++i) {
    v9[i] = expf(v9[i] - mx);
    es += v9[i];
  }
  float inv = 1.f / es;
  float* ob = out_aff + (size_t)b * 9 * HWSZ;
#pragma unroll
  for (int i = 0; i < 9; ++i) ob[(size_t)i * HWSZ + p] = v9[i] * inv;
}

extern "C" void kernel_launch(void* const* d_in, const int* in_sizes, int n_in,
                              void* d_out, int out_size, void* d_ws,
                              size_t ws_size, hipStream_t stream) {
  const float* guidance = (const float*)d_in[0];
  const float* conf_img = (const float*)d_in[1];
  const float* fea = (const float*)d_in[2];
  const float* Wc = (const float*)d_in[3];
  const float* bc = (const float*)d_in[4];
  const float* ascale = (const float*)d_in[5];

  float* out = (float*)d_out;
  float* out_off = out;                           // (4,18,384,384)
  float* out_aff = out + (size_t)Bn * 18 * HWSZ;  // (4,9,384,384)

  float* affc = (float*)d_ws;                       // 4*8*HW floats
  float* cw4 = affc + (size_t)Bn * 8 * HWSZ;        // 4*4*HW floats
  float* Wt = cw4 + (size_t)Bn * 4 * HWSZ;          // 3456 floats

  wtrans_kernel<<<(COUT * CG * 9 + 255) / 256, 256, 0, stream>>>(Wc, Wt);

  int total = Bn * HWSZ;
  int blk = 256;
  conv_kernel<<<Bn * (HH / TS) * (WW / TS), blk, 0, stream>>>(guidance, Wt, bc,
                                                              out_off, affc);
  cw47_kernel<<<total / blk, blk, 0, stream>>>(fea, out_off, cw4);
  main2_kernel<<<(total + blk - 1) / blk, blk, 0, stream>>>(
      fea, conf_img, out_off, affc, cw4, ascale, out_aff);
}

// Round 6
// 290.521 us; speedup vs baseline: 2.0540x; 1.1244x over previous
//
#include <hip/hip_runtime.h>

constexpr int Bn = 4, CG = 16, HH = 384, WW = 384;
constexpr int HWSZ = HH * WW;  // 147456
constexpr int COUT = 24;
constexpr int TSX = 32, TSY = 16;  // conv tile (2 px per thread in x)

// ---------------------------------------------------------------------------
// Weight transpose: Wt[(ic*9+t)*24 + oc] = Wc[(oc*16+ic)*9 + t]
// ---------------------------------------------------------------------------
__global__ void wtrans_kernel(const float* __restrict__ Wc,
                              float* __restrict__ Wt) {
  int i = blockIdx.x * 256 + threadIdx.x;
  if (i < COUT * CG * 9) {
    int oc = i / (CG * 9), rem = i % (CG * 9);
    Wt[rem * COUT + oc] = Wc[i];
  }
}

// ---------------------------------------------------------------------------
// Conv 3x3 SAME 16->24, 32x16 tile, 2 px/thread. Offsets -> d_out layout
// (ch c -> c for c<8, c+2 for c>=8; ch 8,9 zero). Aff channels -> ws planes.
// ---------------------------------------------------------------------------
__global__ __launch_bounds__(256) void conv_kernel(
    const float* __restrict__ g, const float* __restrict__ Wt,
    const float* __restrict__ bc, float* __restrict__ out_off,
    float* __restrict__ affc) {
  __shared__ float lds[CG * 18 * 34];
  int bi = blockIdx.x;
  int bx = (bi % (WW / TSX)) * TSX;
  int by = ((bi / (WW / TSX)) % (HH / TSY)) * TSY;
  int b = bi / ((WW / TSX) * (HH / TSY));
  const float* gb = g + (size_t)b * CG * HWSZ;

  for (int idx = threadIdx.x; idx < CG * 18 * 34; idx += 256) {
    int ic = idx / 612, rem = idx % 612, y = rem / 34, x = rem % 34;
    int gy = by + y - 1, gx = bx + x - 1;
    float v = (gy >= 0 && gy < HH && gx >= 0 && gx < WW)
                  ? gb[ic * HWSZ + gy * WW + gx]
                  : 0.f;
    lds[idx] = v;
  }
  __syncthreads();

  int tx = threadIdx.x & 15, ty = threadIdx.x >> 4;
  float acc0[COUT], acc1[COUT];
#pragma unroll
  for (int oc = 0; oc < COUT; ++oc) {
    float bv = bc[oc];
    acc0[oc] = bv;
    acc1[oc] = bv;
  }

  for (int ic = 0; ic < CG; ++ic) {
    const float* base = lds + ic * 612 + ty * 34 + 2 * tx;
    float vals[3][4];
#pragma unroll
    for (int r = 0; r < 3; ++r) {
      float2 v01 = *(const float2*)(base + r * 34);
      float2 v23 = *(const float2*)(base + r * 34 + 2);
      vals[r][0] = v01.x;
      vals[r][1] = v01.y;
      vals[r][2] = v23.x;
      vals[r][3] = v23.y;
    }
#pragma unroll
    for (int r = 0; r < 3; ++r) {
#pragma unroll
      for (int c3 = 0; c3 < 3; ++c3) {
        float va = vals[r][c3], vb = vals[r][c3 + 1];
        const float* wp = Wt + (ic * 9 + r * 3 + c3) * COUT;
#pragma unroll
        for (int oc = 0; oc < COUT; ++oc) {
          acc0[oc] += va * wp[oc];
          acc1[oc] += vb * wp[oc];
        }
      }
    }
  }

  int p = (by + ty) * WW + bx + 2 * tx;
  float* ob = out_off + (size_t)b * 18 * HWSZ;
#pragma unroll
  for (int c = 0; c < 16; ++c) {
    int c18 = (c < 8) ? c : c + 2;
    *(float2*)(ob + c18 * HWSZ + p) = make_float2(acc0[c], acc1[c]);
  }
  *(float2*)(ob + 8 * HWSZ + p) = make_float2(0.f, 0.f);
  *(float2*)(ob + 9 * HWSZ + p) = make_float2(0.f, 0.f);
  float* ab = affc + (size_t)b * 8 * HWSZ;
#pragma unroll
  for (int c = 0; c < 8; ++c)
    *(float2*)(ab + c * HWSZ + p) = make_float2(acc0[16 + c], acc1[16 + c]);
}

// Bilinear sample, zero padding — identical math to the reference.
__device__ __forceinline__ float bilin_zero(const float* __restrict__ img,
                                            float iy, float ix) {
  float y0f = floorf(iy), x0f = floorf(ix);
  float wy1 = iy - y0f, wx1 = ix - x0f;
  int y0 = (int)y0f, x0 = (int)x0f;
  float acc = 0.f;
#pragma unroll
  for (int dy = 0; dy < 2; ++dy) {
    int yc = y0 + dy;
    bool vy = (yc >= 0) && (yc <= HH - 1);
    int yi = min(max(yc, 0), HH - 1);
    float wy = dy ? wy1 : 1.f - wy1;
#pragma unroll
    for (int dx = 0; dx < 2; ++dx) {
      int xc = x0 + dx;
      bool vx = (xc >= 0) && (xc <= WW - 1);
      int xi = min(max(xc, 0), WW - 1);
      float wx = dx ? wx1 : 1.f - wx1;
      float v = img[yi * WW + xi];
      acc += v * (wy * wx) * ((vy && vx) ? 1.f : 0.f);
    }
  }
  return acc;
}

// ---------------------------------------------------------------------------
// cw for c=0..3 (p-contiguous lanes; samples cluster near (hr,hr)).
// Multiplies aff_conv * cw IN PLACE into the affc plane (single writer).
// ---------------------------------------------------------------------------
__global__ __launch_bounds__(256, 4) void cw03_kernel(
    const float* __restrict__ fea, const float* __restrict__ out_off,
    float* __restrict__ affc) {
  unsigned idx = blockIdx.x * 256u + threadIdx.x;
  unsigned b = idx / (unsigned)HWSZ, p = idx % (unsigned)HWSZ;

  const float* feab = fea + (size_t)b * 8 * HWSZ;
  float feaj[8];
#pragma unroll
  for (int j = 0; j < 8; ++j) feaj[j] = feab[j * HWSZ + p];

  unsigned m0 = 8u * p;
  unsigned a = m0 / (unsigned)HWSZ;
  unsigned r0 = m0 - a * (unsigned)HWSZ;
  unsigned hr = r0 / (unsigned)WW;
  const float* imgA = feab + a * HWSZ;
  const float* offb = out_off + (size_t)b * 18 * HWSZ;
  float* ab = affc + (size_t)b * 8 * HWSZ;
  float cb = (float)hr;

#pragma unroll
  for (int c = 0; c < 4; ++c) {
    const float* dyp = offb + (2 * c) * HWSZ + r0;
    const float* dxp = offb + (2 * c + 1) * HWSZ + r0;
    float4 dy0 = *(const float4*)dyp, dy1 = *(const float4*)(dyp + 4);
    float4 dx0 = *(const float4*)dxp, dx1 = *(const float4*)(dxp + 4);
    float dyv[8] = {dy0.x, dy0.y, dy0.z, dy0.w, dy1.x, dy1.y, dy1.z, dy1.w};
    float dxv[8] = {dx0.x, dx0.y, dx0.z, dx0.w, dx1.x, dx1.y, dx1.z, dx1.w};
    float s = 0.f;
#pragma unroll
    for (int j = 0; j < 8; ++j)
      s += feaj[j] * bilin_zero(imgA, dxv[j] + cb, dyv[j] + cb);
    ab[c * HWSZ + p] *= s;  // av = aff_conv * cos_w
  }
}

// ---------------------------------------------------------------------------
// cw for c=4..7, lane-remapped so wr is wave-uniform (gathers cluster).
// p = a*18432 + 48*Lp + m ; r0 = 384*Lp + 8*m. In-place av multiply.
// ---------------------------------------------------------------------------
__global__ __launch_bounds__(256, 4) void cw47_kernel(
    const float* __restrict__ fea, const float* __restrict__ out_off,
    float* __restrict__ affc) {
  int lane = threadIdx.x & 63, wv = threadIdx.x >> 6;
  int bi = blockIdx.x;
  int Lblk = bi % 6;
  bi /= 6;
  int mblk = bi % 12;
  bi /= 12;
  int a = bi % 8, b = bi / 8;
  int m = mblk * 4 + wv;
  int Lp = Lblk * 64 + lane;
  unsigned p = a * 18432 + 48 * Lp + m;
  unsigned r0 = 384 * Lp + 8 * m;

  const float* feab = fea + (size_t)b * 8 * HWSZ;
  const float* imgA = feab + a * HWSZ;
  const float* offb = out_off + (size_t)b * 18 * HWSZ;
  float* ab = affc + (size_t)b * 8 * HWSZ;

  float feaj[8];
#pragma unroll
  for (int j = 0; j < 8; ++j) feaj[j] = feab[j * HWSZ + p];

#pragma unroll
  for (int c = 4; c < 8; ++c) {
    int chy = 2 * c + 2;
    const float* dyp = offb + chy * HWSZ + r0;
    const float* dxp = offb + (chy + 1) * HWSZ + r0;
    float4 dy0 = *(const float4*)dyp, dy1 = *(const float4*)(dyp + 4);
    float4 dx0 = *(const float4*)dxp, dx1 = *(const float4*)(dxp + 4);
    float dyv[8] = {dy0.x, dy0.y, dy0.z, dy0.w, dy1.x, dy1.y, dy1.z, dy1.w};
    float dxv[8] = {dx0.x, dx0.y, dx0.z, dx0.w, dx1.x, dx1.y, dx1.z, dx1.w};
    float s = 0.f;
#pragma unroll
    for (int j = 0; j < 8; ++j) {
      float cb = (float)(8 * m + j);
      s += feaj[j] * bilin_zero(imgA, dxv[j] + cb, dyv[j] + cb);
    }
    ab[c * HWSZ + p] *= s;
  }
}

__device__ __forceinline__ float fast_tanh(float x) {
  float ax = fabsf(x);
  float e = __expf(2.f * ax);  // inf for large ax -> t = 1 (correct limit)
  float t = 1.f - 2.f * __builtin_amdgcn_rcpf(e + 1.f);
  return copysignf(t, x);
}

// ---------------------------------------------------------------------------
// Epilogue: conf gather + tanh + abs-norm + ref channel + softmax.
// ---------------------------------------------------------------------------
__global__ __launch_bounds__(256) void epilogue_kernel(
    const float* __restrict__ conf_img, const float* __restrict__ out_off,
    const float* __restrict__ affc, const float* __restrict__ aff_scale,
    float* __restrict__ out_aff) {
  unsigned idx = blockIdx.x * 256u + threadIdx.x;
  unsigned b = idx / (unsigned)HWSZ, p = idx % (unsigned)HWSZ;
  unsigned h = p / (unsigned)WW, w = p % (unsigned)WW;

  const float* cimg = conf_img + (size_t)b * HWSZ;
  const float* offb = out_off + (size_t)b * 18 * HWSZ;
  const float* ab = affc + (size_t)b * 8 * HWSZ;
  float invden = __builtin_amdgcn_rcpf(aff_scale[0] + 1e-8f);

  float t[8];
  float asum = 0.f;
#pragma unroll
  for (int c = 0; c < 8; ++c) {
    int chy = (c < 4) ? 2 * c : 2 * c + 2;
    float dy = offb[chy * HWSZ + p];
    float dx = offb[(chy + 1) * HWSZ + p];
    float cf = bilin_zero(cimg, dy + (float)h, dx + (float)w);
    float tv = fast_tanh(ab[c * HWSZ + p]) * invden * cf;
    t[c] = tv;
    asum += fabsf(tv);
  }
  asum += 1e-4f;
  asum = fmaxf(asum, 1.f);
  float inv_asum = __builtin_amdgcn_rcpf(asum);
  float ssum = 0.f;
#pragma unroll
  for (int c = 0; c < 8; ++c) {
    t[c] *= inv_asum;
    ssum += t[c];
  }

  float v9[9];
#pragma unroll
  for (int c = 0; c < 4; ++c) v9[c] = t[c];
  v9[4] = 1.f - ssum;
#pragma unroll
  for (int c = 4; c < 8; ++c) v9[c + 1] = t[c];

  float mx = v9[0];
#pragma unroll
  for (int i = 1; i < 9; ++i) mx = fmaxf(mx, v9[i]);
  float es = 0.f;
#pragma unroll
  for (int i = 0; i < 9; ++i) {
    v9[i] = __expf(v9[i] - mx);
    es += v9[i];
  }
  float inv = __builtin_amdgcn_rcpf(es);
  float* ob = out_aff + (size_t)b * 9 * HWSZ;
#pragma unroll
  for (int i = 0; i < 9; ++i) ob[i * HWSZ + p] = v9[i] * inv;
}

extern "C" void kernel_launch(void* const* d_in, const int* in_sizes, int n_in,
                              void* d_out, int out_size, void* d_ws,
                              size_t ws_size, hipStream_t stream) {
  const float* guidance = (const float*)d_in[0];
  const float* conf_img = (const float*)d_in[1];
  const float* fea = (const float*)d_in[2];
  const float* Wc = (const float*)d_in[3];
  const float* bc = (const float*)d_in[4];
  const float* ascale = (const float*)d_in[5];

  float* out = (float*)d_out;
  float* out_off = out;                           // (4,18,384,384)
  float* out_aff = out + (size_t)Bn * 18 * HWSZ;  // (4,9,384,384)

  float* affc = (float*)d_ws;                        // 4*8*HW floats (18.9MB)
  float* Wt = affc + (size_t)Bn * 8 * HWSZ;          // 3456 floats

  wtrans_kernel<<<(COUT * CG * 9 + 255) / 256, 256, 0, stream>>>(Wc, Wt);

  int total = Bn * HWSZ;
  conv_kernel<<<Bn * (HH / TSY) * (WW / TSX), 256, 0, stream>>>(guidance, Wt,
                                                                bc, out_off,
                                                                affc);
  cw03_kernel<<<total / 256, 256, 0, stream>>>(fea, out_off, affc);
  cw47_kernel<<<total / 256, 256, 0, stream>>>(fea, out_off, affc);
  epilogue_kernel<<<total / 256, 256, 0, stream>>>(conf_img, out_off, affc,
                                                   ascale, out_aff);
}

// Round 7
// 270.629 us; speedup vs baseline: 2.2050x; 1.0735x over previous
//
#include <hip/hip_runtime.h>

constexpr int Bn = 4, CG = 16, HH = 384, WW = 384;
constexpr int HWSZ = HH * WW;  // 147456
constexpr int COUT = 24;
constexpr int TSX = 32, TSY = 16;  // conv tile

// ---------------------------------------------------------------------------
// Weight transpose: Wt[(ic*9+t)*24 + oc] = Wc[(oc*16+ic)*9 + t]
// ---------------------------------------------------------------------------
__global__ void wtrans_kernel(const float* __restrict__ Wc,
                              float* __restrict__ Wt) {
  int i = blockIdx.x * 256 + threadIdx.x;
  if (i < COUT * CG * 9) {
    int oc = i / (CG * 9), rem = i % (CG * 9);
    Wt[rem * COUT + oc] = Wc[i];
  }
}

// ---------------------------------------------------------------------------
// Conv 3x3 SAME 16->24, 32x16 tile, 2 px/thread. Offsets -> d_out layout
// (conv ch c -> out ch c for c<8, c+2 for c>=8; out ch 8,9 zero).
// Aff channels -> ws planes.
// ---------------------------------------------------------------------------
__global__ __launch_bounds__(256) void conv_kernel(
    const float* __restrict__ g, const float* __restrict__ Wt,
    const float* __restrict__ bc, float* __restrict__ out_off,
    float* __restrict__ affc) {
  __shared__ float lds[CG * 18 * 34];
  int bi = blockIdx.x;
  int bx = (bi % (WW / TSX)) * TSX;
  int by = ((bi / (WW / TSX)) % (HH / TSY)) * TSY;
  int b = bi / ((WW / TSX) * (HH / TSY));
  const float* gb = g + (size_t)b * CG * HWSZ;

  for (int idx = threadIdx.x; idx < CG * 18 * 34; idx += 256) {
    int ic = idx / 612, rem = idx % 612, y = rem / 34, x = rem % 34;
    int gy = by + y - 1, gx = bx + x - 1;
    float v = (gy >= 0 && gy < HH && gx >= 0 && gx < WW)
                  ? gb[ic * HWSZ + gy * WW + gx]
                  : 0.f;
    lds[idx] = v;
  }
  __syncthreads();

  int tx = threadIdx.x & 15, ty = threadIdx.x >> 4;
  float acc0[COUT], acc1[COUT];
#pragma unroll
  for (int oc = 0; oc < COUT; ++oc) {
    float bv = bc[oc];
    acc0[oc] = bv;
    acc1[oc] = bv;
  }

  for (int ic = 0; ic < CG; ++ic) {
    const float* base = lds + ic * 612 + ty * 34 + 2 * tx;
    float vals[3][4];
#pragma unroll
    for (int r = 0; r < 3; ++r) {
      float2 v01 = *(const float2*)(base + r * 34);
      float2 v23 = *(const float2*)(base + r * 34 + 2);
      vals[r][0] = v01.x;
      vals[r][1] = v01.y;
      vals[r][2] = v23.x;
      vals[r][3] = v23.y;
    }
#pragma unroll
    for (int r = 0; r < 3; ++r) {
#pragma unroll
      for (int c3 = 0; c3 < 3; ++c3) {
        float va = vals[r][c3], vb = vals[r][c3 + 1];
        const float* wp = Wt + (ic * 9 + r * 3 + c3) * COUT;
#pragma unroll
        for (int oc = 0; oc < COUT; ++oc) {
          acc0[oc] += va * wp[oc];
          acc1[oc] += vb * wp[oc];
        }
      }
    }
  }

  int p = (by + ty) * WW + bx + 2 * tx;
  float* ob = out_off + (size_t)b * 18 * HWSZ;
#pragma unroll
  for (int c = 0; c < 16; ++c) {
    int c18 = (c < 8) ? c : c + 2;
    *(float2*)(ob + c18 * HWSZ + p) = make_float2(acc0[c], acc1[c]);
  }
  *(float2*)(ob + 8 * HWSZ + p) = make_float2(0.f, 0.f);
  *(float2*)(ob + 9 * HWSZ + p) = make_float2(0.f, 0.f);
  float* ab = affc + (size_t)b * 8 * HWSZ;
#pragma unroll
  for (int c = 0; c < 8; ++c)
    *(float2*)(ab + c * HWSZ + p) = make_float2(acc0[16 + c], acc1[16 + c]);
}

// ---------------------------------------------------------------------------
// offT: transpose out_off channels 10..17 (the c>=4 offset planes) from
// [row Lp][col 8m+j] into offT[b][pl][m][Lp][j]  (pl = ch-10).
// cw47b then reads dy/dx with lane-stride 32B (fully coalesced).
// ---------------------------------------------------------------------------
__global__ __launch_bounds__(256) void offt_kernel(
    const float* __restrict__ out_off, float* __restrict__ offT) {
  __shared__ float lds[64][68];
  int bi = blockIdx.x;
  int vt = bi % 6;  bi /= 6;   // 64-col tile (8 m values)
  int lt = bi % 6;  bi /= 6;   // 64-row tile
  int pl = bi % 8;
  int b = bi / 8;
  const float* src =
      out_off + ((size_t)b * 18 + 10 + pl) * HWSZ + (lt * 64) * WW + vt * 64;
  int t = threadIdx.x;
#pragma unroll
  for (int i = 0; i < 4; ++i) {
    int flat = i * 1024 + t * 4;
    int row = flat >> 6, col = flat & 63;
    float4 v = *(const float4*)(src + row * WW + col);
    *(float4*)&lds[row][col] = v;
  }
  __syncthreads();
  int m0 = vt * 8;
  float* dstb = offT + (size_t)(b * 8 + pl) * 48 * 384 * 8;
#pragma unroll
  for (int i = 0; i < 4; ++i) {
    int flat = i * 1024 + t * 4;
    int ml = flat >> 9;
    int r = flat & 511;
    int Lpl = r >> 3, j0 = r & 7;
    float4 v = *(const float4*)&lds[Lpl][8 * ml + j0];
    *(float4*)(dstb + ((size_t)(m0 + ml) * 384 + lt * 64 + Lpl) * 8 + j0) = v;
  }
}

// Bilinear sample, zero padding — identical math to the reference.
__device__ __forceinline__ float bilin_zero(const float* __restrict__ img,
                                            float iy, float ix) {
  float y0f = floorf(iy), x0f = floorf(ix);
  float wy1 = iy - y0f, wx1 = ix - x0f;
  int y0 = (int)y0f, x0 = (int)x0f;
  float acc = 0.f;
#pragma unroll
  for (int dy = 0; dy < 2; ++dy) {
    int yc = y0 + dy;
    bool vy = (yc >= 0) && (yc <= HH - 1);
    int yi = min(max(yc, 0), HH - 1);
    float wy = dy ? wy1 : 1.f - wy1;
#pragma unroll
    for (int dx = 0; dx < 2; ++dx) {
      int xc = x0 + dx;
      bool vx = (xc >= 0) && (xc <= WW - 1);
      int xi = min(max(xc, 0), WW - 1);
      float wx = dx ? wx1 : 1.f - wx1;
      float v = img[yi * WW + xi];
      acc += v * (wy * wx) * ((vy && vx) ? 1.f : 0.f);
    }
  }
  return acc;
}

// ---------------------------------------------------------------------------
// cw for c=4..7: lanes along Lp (gathers cluster at (8m+j, 8m+j)); dy/dx read
// coalesced from offT; result written (write-only) to cw4[b][c'][p].
// ---------------------------------------------------------------------------
__global__ __launch_bounds__(256) void cw47b_kernel(
    const float* __restrict__ fea, const float* __restrict__ offT,
    float* __restrict__ cw4) {
  int lane = threadIdx.x & 63, wv = threadIdx.x >> 6;
  int bi = blockIdx.x;
  int Lblk = bi % 6;  bi /= 6;
  int mblk = bi % 12; bi /= 12;
  int a = bi % 8, b = bi / 8;
  int m = mblk * 4 + wv;
  int Lp = Lblk * 64 + lane;
  unsigned p = a * 18432 + 48 * Lp + m;

  const float* feab = fea + (size_t)b * 8 * HWSZ;
  const float* imgA = feab + a * HWSZ;

  float feaj[8];
#pragma unroll
  for (int j = 0; j < 8; ++j) feaj[j] = feab[j * HWSZ + p];

#pragma unroll
  for (int cp = 0; cp < 4; ++cp) {
    const float* dyp =
        offT + ((size_t)(b * 8 + 2 * cp) * 48 + m) * 384 * 8 + (size_t)Lp * 8;
    const float* dxp =
        offT + ((size_t)(b * 8 + 2 * cp + 1) * 48 + m) * 384 * 8 +
        (size_t)Lp * 8;
    float4 dy0 = *(const float4*)dyp, dy1 = *(const float4*)(dyp + 4);
    float4 dx0 = *(const float4*)dxp, dx1 = *(const float4*)(dxp + 4);
    float dyv[8] = {dy0.x, dy0.y, dy0.z, dy0.w, dy1.x, dy1.y, dy1.z, dy1.w};
    float dxv[8] = {dx0.x, dx0.y, dx0.z, dx0.w, dx1.x, dx1.y, dx1.z, dx1.w};
    float s = 0.f;
#pragma unroll
    for (int j = 0; j < 8; ++j) {
      float cb = (float)(8 * m + j);
      s += feaj[j] * bilin_zero(imgA, dxv[j] + cb, dyv[j] + cb);
    }
    cw4[((size_t)b * 4 + cp) * HWSZ + p] = s;
  }
}

__device__ __forceinline__ float fast_tanh(float x) {
  float ax = fabsf(x);
  float e = __expf(2.f * ax);  // inf for large ax -> t = 1 (correct limit)
  float t = 1.f - 2.f * __builtin_amdgcn_rcpf(e + 1.f);
  return copysignf(t, x);
}

// ---------------------------------------------------------------------------
// Fused cw03 + epilogue. One thread per (b,p), everything p-coalesced except
// the well-clustered gathers. av[c<4] computed in-register; av[c>=4] read
// from cw4. Then conf gather + tanh + abs-norm + ref channel + softmax.
// ---------------------------------------------------------------------------
__global__ __launch_bounds__(256) void fused_kernel(
    const float* __restrict__ fea, const float* __restrict__ conf_img,
    const float* __restrict__ out_off, const float* __restrict__ affc,
    const float* __restrict__ cw4, const float* __restrict__ aff_scale,
    float* __restrict__ out_aff) {
  unsigned idx = blockIdx.x * 256u + threadIdx.x;
  unsigned b = idx / (unsigned)HWSZ, p = idx % (unsigned)HWSZ;
  unsigned h = p / (unsigned)WW, w = p % (unsigned)WW;

  const float* feab = fea + (size_t)b * 8 * HWSZ;
  float feaj[8];
#pragma unroll
  for (int j = 0; j < 8; ++j) feaj[j] = feab[j * HWSZ + p];

  unsigned m0 = 8u * p;
  unsigned a = m0 / (unsigned)HWSZ;
  unsigned r0 = m0 - a * (unsigned)HWSZ;
  unsigned hr = r0 / (unsigned)WW;
  const float* imgA = feab + a * HWSZ;
  const float* offb = out_off + (size_t)b * 18 * HWSZ;
  const float* ab = affc + (size_t)b * 8 * HWSZ;
  float cb = (float)hr;

  float av[8];
#pragma unroll
  for (int c = 0; c < 4; ++c) {
    const float* dyp = offb + (2 * c) * HWSZ + r0;
    const float* dxp = offb + (2 * c + 1) * HWSZ + r0;
    float4 dy0 = *(const float4*)dyp, dy1 = *(const float4*)(dyp + 4);
    float4 dx0 = *(const float4*)dxp, dx1 = *(const float4*)(dxp + 4);
    float dyv[8] = {dy0.x, dy0.y, dy0.z, dy0.w, dy1.x, dy1.y, dy1.z, dy1.w};
    float dxv[8] = {dx0.x, dx0.y, dx0.z, dx0.w, dx1.x, dx1.y, dx1.z, dx1.w};
    float s = 0.f;
#pragma unroll
    for (int j = 0; j < 8; ++j)
      s += feaj[j] * bilin_zero(imgA, dxv[j] + cb, dyv[j] + cb);
    av[c] = ab[c * HWSZ + p] * s;
  }
#pragma unroll
  for (int c = 4; c < 8; ++c)
    av[c] = ab[c * HWSZ + p] * cw4[((size_t)b * 4 + (c - 4)) * HWSZ + p];

  const float* cimg = conf_img + (size_t)b * HWSZ;
  float invden = __builtin_amdgcn_rcpf(aff_scale[0] + 1e-8f);

  float t[8];
  float asum = 0.f;
#pragma unroll
  for (int c = 0; c < 8; ++c) {
    int chy = (c < 4) ? 2 * c : 2 * c + 2;
    float dy = offb[chy * HWSZ + p];
    float dx = offb[(chy + 1) * HWSZ + p];
    float cf = bilin_zero(cimg, dy + (float)h, dx + (float)w);
    float tv = fast_tanh(av[c]) * invden * cf;
    t[c] = tv;
    asum += fabsf(tv);
  }
  asum += 1e-4f;
  asum = fmaxf(asum, 1.f);
  float inv_asum = __builtin_amdgcn_rcpf(asum);
  float ssum = 0.f;
#pragma unroll
  for (int c = 0; c < 8; ++c) {
    t[c] *= inv_asum;
    ssum += t[c];
  }

  float v9[9];
#pragma unroll
  for (int c = 0; c < 4; ++c) v9[c] = t[c];
  v9[4] = 1.f - ssum;
#pragma unroll
  for (int c = 4; c < 8; ++c) v9[c + 1] = t[c];

  float mx = v9[0];
#pragma unroll
  for (int i = 1; i < 9; ++i) mx = fmaxf(mx, v9[i]);
  float es = 0.f;
#pragma unroll
  for (int i = 0; i < 9; ++i) {
    v9[i] = __expf(v9[i] - mx);
    es += v9[i];
  }
  float inv = __builtin_amdgcn_rcpf(es);
  float* ob = out_aff + (size_t)b * 9 * HWSZ;
#pragma unroll
  for (int i = 0; i < 9; ++i) ob[i * HWSZ + p] = v9[i] * inv;
}

extern "C" void kernel_launch(void* const* d_in, const int* in_sizes, int n_in,
                              void* d_out, int out_size, void* d_ws,
                              size_t ws_size, hipStream_t stream) {
  const float* guidance = (const float*)d_in[0];
  const float* conf_img = (const float*)d_in[1];
  const float* fea = (const float*)d_in[2];
  const float* Wc = (const float*)d_in[3];
  const float* bc = (const float*)d_in[4];
  const float* ascale = (const float*)d_in[5];

  float* out = (float*)d_out;
  float* out_off = out;                           // (4,18,384,384)
  float* out_aff = out + (size_t)Bn * 18 * HWSZ;  // (4,9,384,384) final output
  // offT borrows the aff region of d_out (4.72M floats <= 5.31M available);
  // it is consumed by cw47b before fused_kernel overwrites the region.
  float* offT = out_aff;

  float* affc = (float*)d_ws;                     // 4*8*HW floats
  float* cw4 = affc + (size_t)Bn * 8 * HWSZ;      // 4*4*HW floats
  float* Wt = cw4 + (size_t)Bn * 4 * HWSZ;        // 3456 floats

  wtrans_kernel<<<(COUT * CG * 9 + 255) / 256, 256, 0, stream>>>(Wc, Wt);

  int total = Bn * HWSZ;
  conv_kernel<<<Bn * (HH / TSY) * (WW / TSX), 256, 0, stream>>>(guidance, Wt,
                                                                bc, out_off,
                                                                affc);
  offt_kernel<<<Bn * 8 * 6 * 6, 256, 0, stream>>>(out_off, offT);
  cw47b_kernel<<<total / 256, 256, 0, stream>>>(fea, offT, cw4);
  fused_kernel<<<total / 256, 256, 0, stream>>>(fea, conf_img, out_off, affc,
                                                cw4, ascale, out_aff);
}